// Round 2
// baseline (317.792 us; speedup 1.0000x reference)
//
#include <hip/hip_runtime.h>
#include <hip/hip_bf16.h>

#define BLK 128
#define FLAG_OFS 14632   // int slot in ws after the 14632 fp32 weights

__device__ __forceinline__ float bf2f(unsigned short u) {
    union { unsigned int i; float f; } v; v.i = ((unsigned int)u) << 16; return v.f;
}
__device__ __forceinline__ unsigned short f2bf(float f) {
    union { float f; unsigned int i; } v; v.f = f;
    return (unsigned short)((v.i + 0x7FFFu + ((v.i >> 16) & 1u)) >> 16); // RTNE
}

// ws fp32 layout: w0@0(1920) b0@1920(32) w1@1952 b1@2976 w2@3008 b2@4032
// w3@4064 b3@5088 w4@5120 b4@6144 w5@6176(256) b5@6432(8) bank@6440(8192)

struct WP { const void* p[13]; };

// --- dtype sniffer: bf16 data -> nearly all 16-bit halves have exponent-like
// bits; fp32 data -> the 64 low-halves are uniform mantissa bits (~16% pass).
__global__ void pc_sniff(const unsigned short* __restrict__ rel, int* __restrict__ flag) {
    __shared__ int cnt;
    if (threadIdx.x == 0) cnt = 0;
    __syncthreads();
    int local = 0;
    #pragma unroll
    for (int j = 0; j < 2; ++j) {
        unsigned e = (rel[threadIdx.x * 2 + j] >> 7) & 0xFFu;
        if (e >= 100u && e <= 140u) ++local;
    }
    atomicAdd(&cnt, local);
    __syncthreads();
    if (threadIdx.x == 0) *flag = (cnt >= 100) ? 1 : 0;   // 1 = bf16, 0 = fp32
}

__global__ void pc_cvt(WP wp, float* __restrict__ ws, const int* __restrict__ flag) {
    const int sz[13] = {1920,32,1024,32,1024,32,1024,32,1024,32,256,8,8192};
    const int isbf = *flag;
    for (int idx = blockIdx.x * blockDim.x + threadIdx.x; idx < 14632;
         idx += gridDim.x * blockDim.x) {
        int s = 0, off = idx;
        while (off >= sz[s]) { off -= sz[s]; ++s; }
        ws[idx] = isbf ? bf2f(((const unsigned short*)wp.p[s])[off])
                       : ((const float*)wp.p[s])[off];
    }
}

template<int KI>
__device__ __forceinline__ void mlp_layer(
    const unsigned short (*__restrict__ src)[BLK],
    unsigned short (*__restrict__ dst)[BLK],
    const float* __restrict__ w, const float* __restrict__ b, int t)
{
    float acc[32];
    #pragma unroll
    for (int o = 0; o < 32; ++o) acc[o] = b[o];
    #pragma unroll 4
    for (int i = 0; i < KI; ++i) {
        float xi = bf2f(src[i][t]);
        const float* __restrict__ wr = w + i * 32;
        #pragma unroll
        for (int o = 0; o < 32; ++o) acc[o] = fmaf(xi, wr[o], acc[o]);
    }
    #pragma unroll
    for (int o = 0; o < 32; ++o) {
        float v = acc[o];
        v = (v >= 0.0f) ? v : 0.01f * v;   // LeakyReLU(0.01)
        dst[o][t] = f2bf(v);
    }
}

__global__ __launch_bounds__(BLK) void pc_main(
    const void* __restrict__ relv,
    const void* __restrict__ featv,
    const float* __restrict__ ws,
    const int* __restrict__ flag,
    void* __restrict__ outv)
{
    __shared__ unsigned short A[60][BLK];
    __shared__ unsigned short B[32][BLK];
    __shared__ unsigned short F[32][BLK];

    const int t = threadIdx.x;
    const long long n = (long long)blockIdx.x * BLK + t;
    const int isbf = *flag;   // wave-uniform

    if (isbf) {
        const uint2* rp = reinterpret_cast<const uint2*>((const unsigned short*)relv + n * 60);
        #pragma unroll
        for (int j = 0; j < 15; ++j) {
            uint2 d = rp[j];
            A[4*j+0][t] = (unsigned short)(d.x & 0xFFFFu);
            A[4*j+1][t] = (unsigned short)(d.x >> 16);
            A[4*j+2][t] = (unsigned short)(d.y & 0xFFFFu);
            A[4*j+3][t] = (unsigned short)(d.y >> 16);
        }
        const uint4* fp4 = reinterpret_cast<const uint4*>((const unsigned short*)featv + n * 32);
        #pragma unroll
        for (int j = 0; j < 4; ++j) {
            uint4 d = fp4[j];
            F[8*j+0][t] = (unsigned short)(d.x & 0xFFFFu);
            F[8*j+1][t] = (unsigned short)(d.x >> 16);
            F[8*j+2][t] = (unsigned short)(d.y & 0xFFFFu);
            F[8*j+3][t] = (unsigned short)(d.y >> 16);
            F[8*j+4][t] = (unsigned short)(d.z & 0xFFFFu);
            F[8*j+5][t] = (unsigned short)(d.z >> 16);
            F[8*j+6][t] = (unsigned short)(d.w & 0xFFFFu);
            F[8*j+7][t] = (unsigned short)(d.w >> 16);
        }
    } else {
        const float4* rp = reinterpret_cast<const float4*>((const float*)relv + n * 60);
        #pragma unroll
        for (int j = 0; j < 15; ++j) {
            float4 d = rp[j];
            A[4*j+0][t] = f2bf(d.x);
            A[4*j+1][t] = f2bf(d.y);
            A[4*j+2][t] = f2bf(d.z);
            A[4*j+3][t] = f2bf(d.w);
        }
        const float4* fp4 = reinterpret_cast<const float4*>((const float*)featv + n * 32);
        #pragma unroll
        for (int j = 0; j < 8; ++j) {
            float4 d = fp4[j];
            F[4*j+0][t] = f2bf(d.x);
            F[4*j+1][t] = f2bf(d.y);
            F[4*j+2][t] = f2bf(d.z);
            F[4*j+3][t] = f2bf(d.w);
        }
    }

    mlp_layer<60>(A, B, ws + 0,    ws + 1920, t);
    mlp_layer<32>(B, A, ws + 1952, ws + 2976, t);
    mlp_layer<32>(A, B, ws + 3008, ws + 4032, t);
    mlp_layer<32>(B, A, ws + 4064, ws + 5088, t);
    mlp_layer<32>(A, B, ws + 5120, ws + 6144, t);

    // final linear 32->8 (no activation), input in B
    float lg[8];
    {
        const float* __restrict__ w = ws + 6176;
        const float* __restrict__ b = ws + 6432;
        #pragma unroll
        for (int o = 0; o < 8; ++o) lg[o] = b[o];
        #pragma unroll 4
        for (int i = 0; i < 32; ++i) {
            float xi = bf2f(B[i][t]);
            const float* __restrict__ wr = w + i * 8;
            #pragma unroll
            for (int o = 0; o < 8; ++o) lg[o] = fmaf(xi, wr[o], lg[o]);
        }
    }

    // softmax over 8
    float m = lg[0];
    #pragma unroll
    for (int o = 1; o < 8; ++o) m = fmaxf(m, lg[o]);
    float c[8], ssum = 0.0f;
    #pragma unroll
    for (int o = 0; o < 8; ++o) { c[o] = __expf(lg[o] - m); ssum += c[o]; }
    float rs = 1.0f / ssum;
    #pragma unroll
    for (int o = 0; o < 8; ++o) c[o] *= rs;

    // out[o] = sum_i feat_i * sum_k c_k * bank[k][i*32+o]
    float acc[32];
    #pragma unroll
    for (int o = 0; o < 32; ++o) acc[o] = 0.0f;
    const float* __restrict__ bank = ws + 6440;
    #pragma unroll 1
    for (int i = 0; i < 32; ++i) {
        float fi = bf2f(F[i][t]);
        #pragma unroll
        for (int k = 0; k < 8; ++k) {
            float sk = c[k] * fi;
            const float* __restrict__ br = bank + k * 1024 + i * 32;
            #pragma unroll
            for (int o = 0; o < 32; ++o) acc[o] = fmaf(sk, br[o], acc[o]);
        }
    }

    if (isbf) {
        uint4* o4 = reinterpret_cast<uint4*>((unsigned short*)outv + n * 32);
        #pragma unroll
        for (int j = 0; j < 4; ++j) {
            uint4 d;
            d.x = (unsigned)f2bf(acc[8*j+0]) | ((unsigned)f2bf(acc[8*j+1]) << 16);
            d.y = (unsigned)f2bf(acc[8*j+2]) | ((unsigned)f2bf(acc[8*j+3]) << 16);
            d.z = (unsigned)f2bf(acc[8*j+4]) | ((unsigned)f2bf(acc[8*j+5]) << 16);
            d.w = (unsigned)f2bf(acc[8*j+6]) | ((unsigned)f2bf(acc[8*j+7]) << 16);
            o4[j] = d;
        }
    } else {
        float4* o4 = reinterpret_cast<float4*>((float*)outv + n * 32);
        #pragma unroll
        for (int j = 0; j < 8; ++j) {
            float4 d;
            d.x = acc[4*j+0]; d.y = acc[4*j+1]; d.z = acc[4*j+2]; d.w = acc[4*j+3];
            o4[j] = d;
        }
    }
}

extern "C" void kernel_launch(void* const* d_in, const int* in_sizes, int n_in,
                              void* d_out, int out_size, void* d_ws, size_t ws_size,
                              hipStream_t stream)
{
    WP wp;
    for (int i = 0; i < 13; ++i) wp.p[i] = d_in[2 + i];
    float* ws = (float*)d_ws;
    int* flag = (int*)d_ws + FLAG_OFS;

    const int npts = in_sizes[0] / 60;          // 262144
    const int nblk = (npts + BLK - 1) / BLK;    // 2048

    hipLaunchKernelGGL(pc_sniff, dim3(1), dim3(64), 0, stream,
                       (const unsigned short*)d_in[0], flag);
    hipLaunchKernelGGL(pc_cvt, dim3(32), dim3(256), 0, stream, wp, ws, flag);
    hipLaunchKernelGGL(pc_main, dim3(nblk), dim3(BLK), 0, stream,
                       d_in[0], d_in[1], ws, flag, d_out);
}

// Round 3
// 163.217 us; speedup vs baseline: 1.9471x; 1.9471x over previous
//
#include <hip/hip_runtime.h>
#include <stdint.h>

// All I/O fp32 (confirmed R2: WRITE_SIZE == N*32*4 exactly). MFMA bf16 path.
// Per-wave: 16 points. Weights as MFMA A-operand (A[m=out][k]); activations as
// B (B[k][n=point]). Next-layer weights are pre-permuted along their input dim
// (P(k) = 4*(k>>3)+(k&3)+16*((k>>2)&1)) so the D->B handoff between layers is
// 4 in-lane bf16 packs, no cross-lane transpose. Bias enters as MFMA C operand.

typedef __attribute__((ext_vector_type(8))) __bf16 bf16x8;
typedef __attribute__((ext_vector_type(4))) float f32x4;

union FragU { uint32_t u[4]; bf16x8 v; uint4 q; };

__device__ __forceinline__ unsigned short f2bf(float f) {
    union { float f; uint32_t i; } v; v.f = f;
    return (unsigned short)((v.i + 0x7FFFu + ((v.i >> 16) & 1u)) >> 16); // RTNE
}
__device__ __forceinline__ float bf2f(uint32_t u16) {
    union { uint32_t i; float f; } v; v.i = u16 << 16; return v.f;
}
__device__ __forceinline__ uint32_t pk2(float x, float y) {
    return (uint32_t)f2bf(x) | ((uint32_t)f2bf(y) << 16);
}
__device__ __forceinline__ int permK(int k) {
    return 4 * (k >> 3) + (k & 3) + 16 * ((k >> 2) & 1);
}
__device__ __forceinline__ f32x4 MF(bf16x8 a, bf16x8 b, f32x4 c) {
    return __builtin_amdgcn_mfma_f32_16x16x32_bf16(a, b, c, 0, 0, 0);
}

// ws dword layout:
//   [0,1024)    layer0 A-frags  [chunk(2)][tile(2)][lane(64)][dw(4)]  (K=60 pad 64, natural k)
//   [1024,3072) layers1-4 A     [L(4)][tile(2)][lane][dw]             (perm k)
//   [3072,3328) layer5 A        [lane][dw]                            (perm k, rows m>=8 zero)
//   [3328,7424) bank A          [k(8)][tile(2)][lane][dw]             (natural)
//   [7424,9984) bias L0-4 fp32  [L(5)][tile(2)][lane][r(4)]
//   [9984,10240) bias L5 fp32   [lane][r]                             (m>=8 zero)

struct WPf { const float* p[13]; };
// p[0]=w0 p[1]=b0 p[2]=w1 p[3]=b1 ... p[10]=w5 p[11]=b5 p[12]=bank

__global__ void pc_prep(WPf wp, uint32_t* __restrict__ ws) {
    int idx = blockIdx.x * blockDim.x + threadIdx.x;
    if (idx >= 10240) return;
    if (idx < 7424) {
        int layer, t, chunk = 0, lane, d; const float* w; bool perm;
        int r = idx;
        if (r < 1024) { chunk = r >> 9; r &= 511; t = r >> 8; r &= 255; lane = r >> 2; d = r & 3;
                        layer = 0; w = wp.p[0]; perm = false; }
        else if (r < 3072) { r -= 1024; layer = 1 + (r >> 9); r &= 511; t = r >> 8; r &= 255;
                             lane = r >> 2; d = r & 3; w = wp.p[2 * layer]; perm = true; }
        else if (r < 3328) { r -= 3072; layer = 5; t = 0; lane = r >> 2; d = r & 3;
                             w = wp.p[10]; perm = true; }
        else { r -= 3328; int bk = r >> 9; r &= 511; t = r >> 8; r &= 255; lane = r >> 2; d = r & 3;
               layer = -1; w = wp.p[12] + bk * 1024; perm = false; }
        int gq = lane >> 4, m = t * 16 + (lane & 15);
        uint32_t o = 0;
        #pragma unroll
        for (int e = 0; e < 2; ++e) {
            int kf = 8 * gq + 2 * d + e;
            float v = 0.f;
            if (layer == -1) {
                v = w[kf * 32 + m];                       // bank: A[m=o][k=i] = bank[k][i*32+o]
            } else {
                int ks = perm ? permK(kf) : (chunk * 32 + kf);
                if (layer == 0)      { if (ks < 60) v = w[ks * 32 + m]; }
                else if (layer == 5) { if (m < 8)   v = w[ks * 8 + m]; }
                else                 v = w[ks * 32 + m];  // A[m][k] = W[P(k)][m]
            }
            o |= ((uint32_t)f2bf(v)) << (16 * e);
        }
        ws[idx] = o;
    } else if (idx < 9984) {
        int r = idx - 7424; int L = r >> 9; r &= 511; int t = r >> 8; r &= 255;
        int lane = r >> 2, rr = r & 3;
        ((float*)ws)[idx] = wp.p[2 * L + 1][t * 16 + 4 * (lane >> 4) + rr];
    } else {
        int r = idx - 9984; int lane = r >> 2, rr = r & 3;
        int m = 4 * (lane >> 4) + rr;
        ((float*)ws)[idx] = (m < 8) ? wp.p[11][m] : 0.f;
    }
}

#define IT 8

__global__ __launch_bounds__(256, 2) void pc_main(
    const float* __restrict__ rel, const float* __restrict__ feat,
    const uint32_t* __restrict__ wsu, float* __restrict__ out)
{
    const int lane = threadIdx.x & 63;
    const int wv = threadIdx.x >> 6;
    const int g = lane >> 4;
    const int n16 = lane & 15;

    // ---- resident weight fragments (loaded once, reused IT iterations) ----
    bf16x8 A0[2][2], A14[4][2], A5, AB[8][2];
    f32x4 Bi[5][2], Bi5;
    {
        #pragma unroll
        for (int c = 0; c < 2; ++c)
            #pragma unroll
            for (int t = 0; t < 2; ++t) {
                FragU f; f.q = ((const uint4*)(wsu + (c * 2 + t) * 256))[lane];
                A0[c][t] = f.v;
            }
        #pragma unroll
        for (int L = 0; L < 4; ++L)
            #pragma unroll
            for (int t = 0; t < 2; ++t) {
                FragU f; f.q = ((const uint4*)(wsu + 1024 + L * 512 + t * 256))[lane];
                A14[L][t] = f.v;
            }
        { FragU f; f.q = ((const uint4*)(wsu + 3072))[lane]; A5 = f.v; }
        #pragma unroll
        for (int k = 0; k < 8; ++k)
            #pragma unroll
            for (int t = 0; t < 2; ++t) {
                FragU f; f.q = ((const uint4*)(wsu + 3328 + (k * 2 + t) * 256))[lane];
                AB[k][t] = f.v;
            }
        const float* bw = (const float*)wsu;
        #pragma unroll
        for (int L = 0; L < 5; ++L)
            #pragma unroll
            for (int t = 0; t < 2; ++t) {
                float4 b = ((const float4*)(bw + 7424 + L * 512 + t * 256))[lane];
                Bi[L][t][0] = b.x; Bi[L][t][1] = b.y; Bi[L][t][2] = b.z; Bi[L][t][3] = b.w;
            }
        float4 b = ((const float4*)(bw + 9984))[lane];
        Bi5[0] = b.x; Bi5[1] = b.y; Bi5[2] = b.z; Bi5[3] = b.w;
    }

    const size_t pt0 = (size_t)(blockIdx.x * 4 + wv) * (16 * IT);

    for (int it = 0; it < IT; ++it) {
        const size_t n = pt0 + (size_t)it * 16 + n16;

        // ---- layer0 B-frags from rel row (K=60, chunk1 tail zero-padded) ----
        const float* rrow = rel + n * 60;
        float4 ra = *(const float4*)(rrow + 8 * g);
        float4 rb = *(const float4*)(rrow + 8 * g + 4);
        float4 rc = *(const float4*)(rrow + 32 + 8 * g);
        float4 rd = make_float4(0.f, 0.f, 0.f, 0.f);
        if (g < 3) rd = *(const float4*)(rrow + 36 + 8 * g);
        FragU b0, b1;
        b0.u[0] = pk2(ra.x, ra.y); b0.u[1] = pk2(ra.z, ra.w);
        b0.u[2] = pk2(rb.x, rb.y); b0.u[3] = pk2(rb.z, rb.w);
        b1.u[0] = pk2(rc.x, rc.y); b1.u[1] = pk2(rc.z, rc.w);
        b1.u[2] = pk2(rd.x, rd.y); b1.u[3] = pk2(rd.z, rd.w);

        f32x4 t0 = Bi[0][0], t1 = Bi[0][1];
        t0 = MF(A0[0][0], b0.v, t0); t1 = MF(A0[0][1], b0.v, t1);
        t0 = MF(A0[1][0], b1.v, t0); t1 = MF(A0[1][1], b1.v, t1);

        // ---- layers 1..5: leaky -> pack (in-lane) -> mfma with permuted W ----
        #pragma unroll
        for (int L = 0; L < 5; ++L) {
            FragU bx;
            #pragma unroll
            for (int r = 0; r < 4; ++r) {
                t0[r] = fmaxf(t0[r], 0.f) + 0.01f * fminf(t0[r], 0.f);
                t1[r] = fmaxf(t1[r], 0.f) + 0.01f * fminf(t1[r], 0.f);
            }
            bx.u[0] = pk2(t0[0], t0[1]); bx.u[1] = pk2(t0[2], t0[3]);
            bx.u[2] = pk2(t1[0], t1[1]); bx.u[3] = pk2(t1[2], t1[3]);
            if (L < 4) {
                f32x4 n0 = Bi[L + 1][0], n1 = Bi[L + 1][1];
                n0 = MF(A14[L][0], bx.v, n0);
                n1 = MF(A14[L][1], bx.v, n1);
                t0 = n0; t1 = n1;
            } else {
                t0 = MF(A5, bx.v, Bi5);   // logits: groups 0,1 hold m=0..7
            }
        }

        // ---- softmax over 8 logits (lanes n16 / n16+16 pair via xor-16) ----
        float m4 = fmaxf(fmaxf(t0[0], t0[1]), fmaxf(t0[2], t0[3]));
        float m8 = fmaxf(m4, __shfl_xor(m4, 16, 64));
        float e0 = __expf(t0[0] - m8), e1 = __expf(t0[1] - m8);
        float e2 = __expf(t0[2] - m8), e3 = __expf(t0[3] - m8);
        float s4 = e0 + e1 + e2 + e3;
        float s8 = s4 + __shfl_xor(s4, 16, 64);
        float inv = 1.0f / s8;
        uint32_t pc01 = pk2(e0 * inv, e1 * inv);
        uint32_t pc23 = pk2(e2 * inv, e3 * inv);
        uint32_t q01 = (uint32_t)__builtin_amdgcn_ds_bpermute(n16 * 4, (int)pc01);
        uint32_t q23 = (uint32_t)__builtin_amdgcn_ds_bpermute(n16 * 4, (int)pc23);
        uint32_t q45 = (uint32_t)__builtin_amdgcn_ds_bpermute((n16 + 16) * 4, (int)pc01);
        uint32_t q67 = (uint32_t)__builtin_amdgcn_ds_bpermute((n16 + 16) * 4, (int)pc23);
        float cw[8] = { bf2f(q01 & 0xffff), bf2f(q01 >> 16),
                        bf2f(q23 & 0xffff), bf2f(q23 >> 16),
                        bf2f(q45 & 0xffff), bf2f(q45 >> 16),
                        bf2f(q67 & 0xffff), bf2f(q67 >> 16) };

        // ---- bank stage: out = sum_k c_k * (feat . Bank_k) ----
        const float* frow = feat + n * 32 + 8 * g;
        float4 fa = *(const float4*)frow;
        float4 fb = *(const float4*)(frow + 4);
        FragU bf_;
        bf_.u[0] = pk2(fa.x, fa.y); bf_.u[1] = pk2(fa.z, fa.w);
        bf_.u[2] = pk2(fb.x, fb.y); bf_.u[3] = pk2(fb.z, fb.w);

        f32x4 o0 = {0.f, 0.f, 0.f, 0.f}, o1 = {0.f, 0.f, 0.f, 0.f};
        #pragma unroll
        for (int k = 0; k < 8; ++k) {
            f32x4 z = {0.f, 0.f, 0.f, 0.f};
            f32x4 u0 = MF(AB[k][0], bf_.v, z);
            f32x4 u1 = MF(AB[k][1], bf_.v, z);
            #pragma unroll
            for (int r = 0; r < 4; ++r) { o0[r] += cw[k] * u0[r]; o1[r] += cw[k] * u1[r]; }
        }

        float* orow = out + n * 32;
        *(float4*)(orow + 4 * g)      = make_float4(o0[0], o0[1], o0[2], o0[3]);
        *(float4*)(orow + 16 + 4 * g) = make_float4(o1[0], o1[1], o1[2], o1[3]);
    }
}

extern "C" void kernel_launch(void* const* d_in, const int* in_sizes, int n_in,
                              void* d_out, int out_size, void* d_ws, size_t ws_size,
                              hipStream_t stream)
{
    const float* rel = (const float*)d_in[0];
    const float* feat = (const float*)d_in[1];
    WPf wp;
    for (int i = 0; i < 13; ++i) wp.p[i] = (const float*)d_in[2 + i];
    uint32_t* ws = (uint32_t*)d_ws;
    float* out = (float*)d_out;

    const int npts = in_sizes[0] / 60;            // 262144
    const int nwaves = npts / (16 * IT);          // 2048
    const int nblocks = nwaves / 4;               // 512

    hipLaunchKernelGGL(pc_prep, dim3(40), dim3(256), 0, stream, wp, ws);
    hipLaunchKernelGGL(pc_main, dim3(nblocks), dim3(256), 0, stream, rel, feat, ws, out);
}

// Round 4
// 160.180 us; speedup vs baseline: 1.9840x; 1.0190x over previous
//
#include <hip/hip_runtime.h>
#include <stdint.h>

// All I/O fp32. MFMA bf16 path, weights as A-operand (A[m=out][k]), activations
// as B (B[k][n=point]). Layer->layer D->B handoff is in-lane only because each
// next layer's weights are pre-permuted along input dim:
//   P(k) = 4*(k>>3) + (k&3) + 16*((k>>2)&1)
// R4: all weight frags staged to LDS per block (compiler couldn't keep 160
// VGPR of weights resident -> was re-loading from global each iter = latency
// bound, MfmaUtil 6.5%). Two independent 16-point groups interleaved per
// iteration for ILP + weight-read amortization. Biases resident in VGPR.

typedef __attribute__((ext_vector_type(8))) __bf16 bf16x8;
typedef __attribute__((ext_vector_type(4))) float f32x4;

union FragU { uint32_t u[4]; bf16x8 v; uint4 q; };

__device__ __forceinline__ unsigned short f2bf(float f) {
    union { float f; uint32_t i; } v; v.f = f;
    return (unsigned short)((v.i + 0x7FFFu + ((v.i >> 16) & 1u)) >> 16); // RTNE
}
__device__ __forceinline__ float bf2f(uint32_t u16) {
    union { uint32_t i; float f; } v; v.i = u16 << 16; return v.f;
}
__device__ __forceinline__ uint32_t pk2(float x, float y) {
    return (uint32_t)f2bf(x) | ((uint32_t)f2bf(y) << 16);
}
__device__ __forceinline__ int permK(int k) {
    return 4 * (k >> 3) + (k & 3) + 16 * ((k >> 2) & 1);
}
__device__ __forceinline__ f32x4 MF(bf16x8 a, bf16x8 b, f32x4 c) {
    return __builtin_amdgcn_mfma_f32_16x16x32_bf16(a, b, c, 0, 0, 0);
}

// ws dword layout (10240 dwords):
//   [0,1024)    layer0 A-frags  [chunk(2)][tile(2)][lane(64)][dw(4)]  (K=60 pad 64)
//   [1024,3072) layers1-4 A     [L(4)][tile(2)][lane][dw]             (perm k)
//   [3072,3328) layer5 A        [lane][dw]                            (perm k, m>=8 zero)
//   [3328,7424) bank A          [k(8)][tile(2)][lane][dw]
//   [7424,9984) bias L0-4 fp32  [L(5)][tile(2)][lane][r(4)]
//   [9984,10240) bias L5 fp32   [lane][r]                             (m>=8 zero)

struct WPf { const float* p[13]; };

__global__ void pc_prep(WPf wp, uint32_t* __restrict__ ws) {
    int idx = blockIdx.x * blockDim.x + threadIdx.x;
    if (idx >= 10240) return;
    if (idx < 7424) {
        int layer, t, chunk = 0, lane, d; const float* w; bool perm;
        int r = idx;
        if (r < 1024) { chunk = r >> 9; r &= 511; t = r >> 8; r &= 255; lane = r >> 2; d = r & 3;
                        layer = 0; w = wp.p[0]; perm = false; }
        else if (r < 3072) { r -= 1024; layer = 1 + (r >> 9); r &= 511; t = r >> 8; r &= 255;
                             lane = r >> 2; d = r & 3; w = wp.p[2 * layer]; perm = true; }
        else if (r < 3328) { r -= 3072; layer = 5; t = 0; lane = r >> 2; d = r & 3;
                             w = wp.p[10]; perm = true; }
        else { r -= 3328; int bk = r >> 9; r &= 511; t = r >> 8; r &= 255; lane = r >> 2; d = r & 3;
               layer = -1; w = wp.p[12] + bk * 1024; perm = false; }
        int gq = lane >> 4, m = t * 16 + (lane & 15);
        uint32_t o = 0;
        #pragma unroll
        for (int e = 0; e < 2; ++e) {
            int kf = 8 * gq + 2 * d + e;
            float v = 0.f;
            if (layer == -1) {
                v = w[kf * 32 + m];                       // bank: A[m=o][k=i] = bank[k][i*32+o]
            } else {
                int ks = perm ? permK(kf) : (chunk * 32 + kf);
                if (layer == 0)      { if (ks < 60) v = w[ks * 32 + m]; }
                else if (layer == 5) { if (m < 8)   v = w[ks * 8 + m]; }
                else                 v = w[ks * 32 + m];  // A[m][k] = W[P(k)][m]
            }
            o |= ((uint32_t)f2bf(v)) << (16 * e);
        }
        ws[idx] = o;
    } else if (idx < 9984) {
        int r = idx - 7424; int L = r >> 9; r &= 511; int t = r >> 8; r &= 255;
        int lane = r >> 2, rr = r & 3;
        ((float*)ws)[idx] = wp.p[2 * L + 1][t * 16 + 4 * (lane >> 4) + rr];
    } else {
        int r = idx - 9984; int lane = r >> 2, rr = r & 3;
        int m = 4 * (lane >> 4) + rr;
        ((float*)ws)[idx] = (m < 8) ? wp.p[11][m] : 0.f;
    }
}

#define IT 4   // 32 points/iter * 4 iters = 128 points per wave; 2048 waves

__global__ __launch_bounds__(256, 2) void pc_main(
    const float* __restrict__ rel, const float* __restrict__ feat,
    const uint32_t* __restrict__ wsu, float* __restrict__ out)
{
    __shared__ __align__(16) uint32_t W[10240];   // 40 KB
    { // cooperative stage of all frags/biases: 2560 x uint4
        uint4* s4 = (uint4*)W;
        const uint4* g4 = (const uint4*)wsu;
        #pragma unroll
        for (int i = 0; i < 10; ++i) s4[threadIdx.x + 256 * i] = g4[threadIdx.x + 256 * i];
    }
    __syncthreads();

    const int lane = threadIdx.x & 63;
    const int wv = threadIdx.x >> 6;
    const int g = lane >> 4;
    const int n16 = lane & 15;

    // resident biases (C-operands)
    f32x4 Bi[5][2], Bi5;
    #pragma unroll
    for (int L = 0; L < 5; ++L)
        #pragma unroll
        for (int t = 0; t < 2; ++t) {
            float4 b = ((const float4*)(W + 7424 + L * 512 + t * 256))[lane];
            Bi[L][t][0] = b.x; Bi[L][t][1] = b.y; Bi[L][t][2] = b.z; Bi[L][t][3] = b.w;
        }
    {
        float4 b = ((const float4*)(W + 9984))[lane];
        Bi5[0] = b.x; Bi5[1] = b.y; Bi5[2] = b.z; Bi5[3] = b.w;
    }

    const size_t pt0 = (size_t)(blockIdx.x * 4 + wv) * (32 * IT);

    #define LDF(off) ({ FragU _f; _f.q = ((const uint4*)(W + (off)))[lane]; _f.v; })

    for (int it = 0; it < IT; ++it) {
        const size_t nA = pt0 + (size_t)it * 32 + n16;   // group 0 point; group 1 = +16

        // ---- layer0 B-frags (K=60, tail pad) for both groups ----
        FragU c0[2], c1[2];
        #pragma unroll
        for (int q = 0; q < 2; ++q) {
            const float* rrow = rel + (nA + 16 * q) * 60;
            float4 ra = *(const float4*)(rrow + 8 * g);
            float4 rb = *(const float4*)(rrow + 8 * g + 4);
            float4 rc = *(const float4*)(rrow + 32 + 8 * g);
            float4 rd = make_float4(0.f, 0.f, 0.f, 0.f);
            if (g < 3) rd = *(const float4*)(rrow + 36 + 8 * g);
            c0[q].u[0] = pk2(ra.x, ra.y); c0[q].u[1] = pk2(ra.z, ra.w);
            c0[q].u[2] = pk2(rb.x, rb.y); c0[q].u[3] = pk2(rb.z, rb.w);
            c1[q].u[0] = pk2(rc.x, rc.y); c1[q].u[1] = pk2(rc.z, rc.w);
            c1[q].u[2] = pk2(rd.x, rd.y); c1[q].u[3] = pk2(rd.z, rd.w);
        }

        f32x4 t0[2], t1[2];
        #pragma unroll
        for (int q = 0; q < 2; ++q) { t0[q] = Bi[0][0]; t1[q] = Bi[0][1]; }
        {
            bf16x8 w00 = LDF(0), w01 = LDF(256), w10 = LDF(512), w11 = LDF(768);
            #pragma unroll
            for (int q = 0; q < 2; ++q) {
                t0[q] = MF(w00, c0[q].v, t0[q]); t1[q] = MF(w01, c0[q].v, t1[q]);
                t0[q] = MF(w10, c1[q].v, t0[q]); t1[q] = MF(w11, c1[q].v, t1[q]);
            }
        }

        // ---- layers 1..4: leaky -> in-lane pack -> mfma (perm weights) ----
        #pragma unroll
        for (int L = 0; L < 4; ++L) {
            bf16x8 wa = LDF(1024 + L * 512), wb = LDF(1024 + L * 512 + 256);
            #pragma unroll
            for (int q = 0; q < 2; ++q) {
                FragU bx;
                #pragma unroll
                for (int r = 0; r < 4; ++r) {
                    t0[q][r] = fmaxf(t0[q][r], 0.01f * t0[q][r]);
                    t1[q][r] = fmaxf(t1[q][r], 0.01f * t1[q][r]);
                }
                bx.u[0] = pk2(t0[q][0], t0[q][1]); bx.u[1] = pk2(t0[q][2], t0[q][3]);
                bx.u[2] = pk2(t1[q][0], t1[q][1]); bx.u[3] = pk2(t1[q][2], t1[q][3]);
                t0[q] = MF(wa, bx.v, Bi[L + 1][0]);
                t1[q] = MF(wb, bx.v, Bi[L + 1][1]);
            }
        }

        // ---- layer5 (32->8) ----
        {
            bf16x8 w5 = LDF(3072);
            #pragma unroll
            for (int q = 0; q < 2; ++q) {
                FragU bx;
                #pragma unroll
                for (int r = 0; r < 4; ++r) {
                    t0[q][r] = fmaxf(t0[q][r], 0.01f * t0[q][r]);
                    t1[q][r] = fmaxf(t1[q][r], 0.01f * t1[q][r]);
                }
                bx.u[0] = pk2(t0[q][0], t0[q][1]); bx.u[1] = pk2(t0[q][2], t0[q][3]);
                bx.u[2] = pk2(t1[q][0], t1[q][1]); bx.u[3] = pk2(t1[q][2], t1[q][3]);
                t0[q] = MF(w5, bx.v, Bi5);   // logits m0..3 in g=0, m4..7 in g=1
            }
        }

        // ---- softmax over 8 per point, broadcast coeffs to all 4 g-groups ----
        float cw[2][8];
        #pragma unroll
        for (int q = 0; q < 2; ++q) {
            float m4 = fmaxf(fmaxf(t0[q][0], t0[q][1]), fmaxf(t0[q][2], t0[q][3]));
            float m8 = fmaxf(m4, __shfl_xor(m4, 16, 64));
            float e0 = __expf(t0[q][0] - m8), e1 = __expf(t0[q][1] - m8);
            float e2 = __expf(t0[q][2] - m8), e3 = __expf(t0[q][3] - m8);
            float s4 = e0 + e1 + e2 + e3;
            float s8 = s4 + __shfl_xor(s4, 16, 64);
            float inv = 1.0f / s8;
            uint32_t p01 = pk2(e0 * inv, e1 * inv);
            uint32_t p23 = pk2(e2 * inv, e3 * inv);
            uint32_t q01 = (uint32_t)__builtin_amdgcn_ds_bpermute(n16 * 4, (int)p01);
            uint32_t q23 = (uint32_t)__builtin_amdgcn_ds_bpermute(n16 * 4, (int)p23);
            uint32_t q45 = (uint32_t)__builtin_amdgcn_ds_bpermute((n16 + 16) * 4, (int)p01);
            uint32_t q67 = (uint32_t)__builtin_amdgcn_ds_bpermute((n16 + 16) * 4, (int)p23);
            cw[q][0] = bf2f(q01 & 0xffff); cw[q][1] = bf2f(q01 >> 16);
            cw[q][2] = bf2f(q23 & 0xffff); cw[q][3] = bf2f(q23 >> 16);
            cw[q][4] = bf2f(q45 & 0xffff); cw[q][5] = bf2f(q45 >> 16);
            cw[q][6] = bf2f(q67 & 0xffff); cw[q][7] = bf2f(q67 >> 16);
        }

        // ---- bank stage: out = sum_k c_k * (Bank_k . feat) ----
        FragU bf_[2];
        #pragma unroll
        for (int q = 0; q < 2; ++q) {
            const float* frow = feat + (nA + 16 * q) * 32 + 8 * g;
            float4 fa = *(const float4*)frow;
            float4 fb = *(const float4*)(frow + 4);
            bf_[q].u[0] = pk2(fa.x, fa.y); bf_[q].u[1] = pk2(fa.z, fa.w);
            bf_[q].u[2] = pk2(fb.x, fb.y); bf_[q].u[3] = pk2(fb.z, fb.w);
        }
        f32x4 o0[2], o1[2];
        #pragma unroll
        for (int q = 0; q < 2; ++q) {
            o0[q] = (f32x4){0.f, 0.f, 0.f, 0.f};
            o1[q] = (f32x4){0.f, 0.f, 0.f, 0.f};
        }
        #pragma unroll
        for (int k = 0; k < 8; ++k) {
            bf16x8 wk0 = LDF(3328 + k * 512), wk1 = LDF(3328 + k * 512 + 256);
            #pragma unroll
            for (int q = 0; q < 2; ++q) {
                f32x4 z = {0.f, 0.f, 0.f, 0.f};
                f32x4 u0 = MF(wk0, bf_[q].v, z);
                f32x4 u1 = MF(wk1, bf_[q].v, z);
                #pragma unroll
                for (int r = 0; r < 4; ++r) {
                    o0[q][r] += cw[q][k] * u0[r];
                    o1[q][r] += cw[q][k] * u1[r];
                }
            }
        }

        #pragma unroll
        for (int q = 0; q < 2; ++q) {
            float* orow = out + (nA + 16 * q) * 32;
            *(float4*)(orow + 4 * g)      = make_float4(o0[q][0], o0[q][1], o0[q][2], o0[q][3]);
            *(float4*)(orow + 16 + 4 * g) = make_float4(o1[q][0], o1[q][1], o1[q][2], o1[q][3]);
        }
    }
    #undef LDF
}

extern "C" void kernel_launch(void* const* d_in, const int* in_sizes, int n_in,
                              void* d_out, int out_size, void* d_ws, size_t ws_size,
                              hipStream_t stream)
{
    const float* rel = (const float*)d_in[0];
    const float* feat = (const float*)d_in[1];
    WPf wp;
    for (int i = 0; i < 13; ++i) wp.p[i] = (const float*)d_in[2 + i];
    uint32_t* ws = (uint32_t*)d_ws;
    float* out = (float*)d_out;

    const int npts = in_sizes[0] / 60;                 // 262144
    const int nblocks = npts / (32 * IT * 4);          // 512

    hipLaunchKernelGGL(pc_prep, dim3(40), dim3(256), 0, stream, wp, ws);
    hipLaunchKernelGGL(pc_main, dim3(nblocks), dim3(256), 0, stream, rel, feat, ws, out);
}